// Round 9
// baseline (3338.983 us; speedup 1.0000x reference)
//
#include <hip/hip_runtime.h>

// ---------------------------------------------------------------------------
// StackedBidirectionalLstm  (B=32, T=512, IN=512, H=512, LAYERS=2, bidir, highway)
//
// Round 9 = round 6's proven MALL exchange protocol (sc0 sc1, 16B chunks
// {6 bf16 | enc(s)}, poll-on-data) + round 8's structure, minus the broken
// hand-issued px loads:
//   - 8-wave WGs (512 thr): wf[5][4] = 80 VGPR/wave, weights register-resident
//   - ONE barrier/step (part double-buffered)
//   - publish immediately after ht
//   - px: C-level loads, register double-buffer xCur/xNext; xNext issued for
//     s+1 right after poll s; compiler-managed waitcnts (no asm liveness bug)
//
//   ws layout (bytes), total ~202.4 MiB:
//     px   @ 0          201,326,592  ([2][512*32][3072] bf16, t-major)
//     whp  @ 201326592   10,485,760  (packed Wh fragments)
//     hxc  @ 211812352      393,216  ([2 layer][2 buf][8 grp][16 m][8 r][6 c]x16B)
//   d_out scratch: phase A xbf/wxt0/wxt1, phase B a1bf (as previous rounds).
// ---------------------------------------------------------------------------

typedef float f32x4 __attribute__((ext_vector_type(4)));
typedef __bf16 bf16x8 __attribute__((ext_vector_type(8)));
typedef unsigned short us8 __attribute__((ext_vector_type(8)));
typedef unsigned short us4 __attribute__((ext_vector_type(4)));
typedef unsigned int u32x4 __attribute__((ext_vector_type(4)));

__device__ __forceinline__ unsigned short f2bf(float f) {
  unsigned int u = __float_as_uint(f);
  u += 0x7FFFu + ((u >> 16) & 1u);            // round-to-nearest-even
  return (unsigned short)(u >> 16);
}
__device__ __forceinline__ float bf2f(unsigned int h) {
  return __uint_as_float(h << 16);
}
__device__ __forceinline__ float sigf(float x) { return 1.0f / (1.0f + __expf(-x)); }
__device__ __forceinline__ float tanh_(float x) { return 2.0f / (1.0f + __expf(-2.0f * x)) - 1.0f; }

#define MFMA(a, b, c) __builtin_amdgcn_mfma_f32_16x16x32_bf16((a), (b), (c), 0, 0, 0)
#define GLOAD_LDS(gp, lp)                                                           \
  __builtin_amdgcn_global_load_lds(                                                 \
      (const __attribute__((address_space(1))) void*)(gp),                          \
      (__attribute__((address_space(3))) void*)(lp), 16, 0, 0)

// Coherent (device/system-scope) 16B pair load; no waitcnt inside.
__device__ __forceinline__ void chunk2_ld(const char* p, u32x4& a, u32x4& b) {
  asm volatile("global_load_dwordx4 %0, %2, off sc0 sc1\n\t"
               "global_load_dwordx4 %1, %2, off offset:16 sc0 sc1"
               : "=&v"(a), "=&v"(b) : "v"(p) : "memory");
}
// Fire-and-forget coherent 16B publish.
__device__ __forceinline__ void pub16(char* p, u32x4 v) {
  asm volatile("global_store_dwordx4 %0, %1, off sc0 sc1" :: "v"(p), "v"(v) : "memory");
}

// --------------------------- prep kernels ----------------------------------

__global__ void k_convert_x(const float* __restrict__ x, unsigned short* __restrict__ xb, int n4) {
  int i = blockIdx.x * blockDim.x + threadIdx.x;
  if (i < n4) {
    float4 v = ((const float4*)x)[i];
    us4 o;
    o[0] = f2bf(v.x); o[1] = f2bf(v.y); o[2] = f2bf(v.z); o[3] = f2bf(v.w);
    ((us4*)xb)[i] = o;
  }
}

// Tiled transpose: WxT[n][k] = bf16(Wx[k][n]); z = layer*2+dir
__global__ __launch_bounds__(256) void k_pack_wxT(
    const float* __restrict__ W0, const float* __restrict__ W1,
    const float* __restrict__ W2, const float* __restrict__ W3,
    unsigned short* __restrict__ o01, unsigned short* __restrict__ o23) {
  int y = blockIdx.z;
  int K = (y >> 1) ? 1024 : 512;
  int kb = blockIdx.y * 32;
  if (kb >= K) return;
  const float* W = (y == 0) ? W0 : (y == 1) ? W1 : (y == 2) ? W2 : W3;
  unsigned short* o = (y >> 1) ? (o23 + (size_t)(y & 1) * 3072 * 1024)
                               : (o01 + (size_t)(y & 1) * 3072 * 512);
  __shared__ float tile[32][33];
  int nb = blockIdx.x * 32;
  int tx = threadIdx.x & 31, ty = threadIdx.x >> 5;   // ty 0..7
#pragma unroll
  for (int r = 0; r < 4; ++r)
    tile[ty + r * 8][tx] = W[(size_t)(kb + ty + r * 8) * 3072 + nb + tx];
  __syncthreads();
#pragma unroll
  for (int r = 0; r < 4; ++r)
    o[(size_t)(nb + ty + r * 8) * K + kb + tx] = f2bf(tile[tx][ty + r * 8]);
}

// Pack Wh (512x2560 f32) into MFMA B-fragments:
// out[(((g*32+ns)*16+ks)*64+lane)*8+e] = Wh[ks*32+(lane>>4)*8+e][g*512+ns*16+(lane&15)]
__global__ void k_pack_whp(const float* __restrict__ W0, const float* __restrict__ W1,
                           const float* __restrict__ W2, const float* __restrict__ W3,
                           unsigned short* __restrict__ out) {
  int y = blockIdx.y;
  const float* W = (y == 0) ? W0 : (y == 1) ? W1 : (y == 2) ? W2 : W3;
  unsigned short* o = out + (size_t)y * 1310720;
  int v = blockIdx.x * 256 + threadIdx.x;   // < 163840
  int lane = v & 63, ks = (v >> 6) & 15, ns = (v >> 10) & 31, g = v >> 15;
  int col = g * 512 + ns * 16 + (lane & 15);
  int kb = ks * 32 + ((lane >> 4) << 3);
  us8 vec;
#pragma unroll
  for (int e = 0; e < 8; ++e) vec[e] = f2bf(W[(size_t)(kb + e) * 2560 + col]);
  *(us8*)&o[(size_t)v * 8] = vec;
}

__device__ __forceinline__ unsigned short f2bf(float f);

// --------------------------- bf16 GEMM -------------------------------------
// px[rr][col] with rr = t*32+b (t-major), from A[16384][K] @ Bt[3072][K]^T.
__global__ __launch_bounds__(256) void k_gemm(const unsigned short* __restrict__ A,
                                              const unsigned short* __restrict__ BtBase,
                                              unsigned short* __restrict__ CBase, int K) {
  __shared__ __align__(128) unsigned short As[128 * 32];
  __shared__ __align__(128) unsigned short Bs[128 * 32];
  const unsigned short* Bt = BtBase + (size_t)blockIdx.z * 3072 * K;
  unsigned short* C = CBase + (size_t)blockIdx.z * 16384 * 3072;
  int tid = threadIdx.x;
  int w = tid >> 6, l = tid & 63;
  int m0 = blockIdx.x * 128, n0 = blockIdx.y * 128;
  int wr = (w >> 1) * 64, wc = (w & 1) * 64;
  f32x4 acc[4][4];
#pragma unroll
  for (int i = 0; i < 4; ++i)
#pragma unroll
    for (int j = 0; j < 4; ++j) acc[i][j] = (f32x4){0.f, 0.f, 0.f, 0.f};

  for (int k0 = 0; k0 < K; k0 += 32) {
    __syncthreads();
#pragma unroll
    for (int half = 0; half < 2; ++half) {
      int r = w * 32 + half * 16 + (l >> 2);     // row within tile
      int gq = (l & 3) ^ (r & 3);                // swizzled source quarter
      GLOAD_LDS(A + (size_t)(m0 + r) * K + k0 + gq * 8, &As[(w * 32 + half * 16) * 32]);
      GLOAD_LDS(Bt + (size_t)(n0 + r) * K + k0 + gq * 8, &Bs[(w * 32 + half * 16) * 32]);
    }
    __syncthreads();
    bf16x8 af[4], bfr[4];
#pragma unroll
    for (int mi = 0; mi < 4; ++mi) {
      int r = wr + mi * 16 + (l & 15);
      int q = (l >> 4) ^ (r & 3);
      af[mi] = __builtin_bit_cast(bf16x8, *(const us8*)&As[r * 32 + q * 8]);
    }
#pragma unroll
    for (int ni = 0; ni < 4; ++ni) {
      int r = wc + ni * 16 + (l & 15);
      int q = (l >> 4) ^ (r & 3);
      bfr[ni] = __builtin_bit_cast(bf16x8, *(const us8*)&Bs[r * 32 + q * 8]);
    }
#pragma unroll
    for (int mi = 0; mi < 4; ++mi)
#pragma unroll
      for (int ni = 0; ni < 4; ++ni) acc[mi][ni] = MFMA(af[mi], bfr[ni], acc[mi][ni]);
  }
#pragma unroll
  for (int mi = 0; mi < 4; ++mi)
#pragma unroll
    for (int ni = 0; ni < 4; ++ni)
#pragma unroll
      for (int r4 = 0; r4 < 4; ++r4) {
        int row = m0 + wr + mi * 16 + (l >> 4) * 4 + r4;    // b*512 + t
        int rr = ((row & 511) << 5) + (row >> 9);           // t*32 + b
        int col = n0 + wc + ni * 16 + (l & 15);
        C[(size_t)rr * 3072 + col] = f2bf(acc[mi][ni][r4]);
      }
}

// --------------------------- persistent LSTM layer -------------------------
// 128 WGs x 512 threads = 8 groups (dir d, batch-quarter q) x 16 members.
// Member m owns hidden units m*32..m*32+31. 8 waves: kh = w&3 (K quarter),
// nh = w>>2 (hidden half); wf[5][4] = 80 VGPR/wave, register-resident.
// h exchange: 16B chunks {6 bf16 | enc(s)} via sc0 sc1 (MALL-coherent).
__global__ __launch_bounds__(512, 1) void k_persist(
    const unsigned short* __restrict__ px,    // [2][512*32][3072] bf16 t-major
    const unsigned short* __restrict__ wp,    // this layer's packed Wh (2 dirs)
    const float* __restrict__ bias_f, const float* __restrict__ bias_b,
    char* __restrict__ hxc,                   // [2 layer][2 buf][8 grp][16 m][8 r][6 c]x16B
    unsigned short* __restrict__ ybf,         // layer0: a1bf, else null
    float* __restrict__ yf,                   // layer1: d_out, else null
    float* __restrict__ finals,               // d_out + 16777216
    int layer) {
  __shared__ float part[2][4][8][160];        // 40 KiB, double-buffered
  int wg = blockIdx.x;
  int grp = wg >> 4, m = wg & 15;
  int d = grp & 1, q = grp >> 1;
  int tid = threadIdx.x;
  int w = tid >> 6, l = tid & 63;
  int kh = w & 3, nh = w >> 2;
  int ns = m * 2 + nh;                        // 16-hidden slice id (0..31)
  const unsigned short* wpd = wp + (size_t)d * 1310720;
  const unsigned short* pxd = px + (size_t)d * 16384 * 3072;
  const float* bias = d ? bias_b : bias_f;
  char* hxg = hxc + (size_t)layer * 196608 + (size_t)grp * 12288;

  // ---- Wh fragments register-resident: wf[gate][kk], this wave's K-quarter
  bf16x8 wf[5][4];
#pragma unroll
  for (int g5 = 0; g5 < 5; ++g5)
#pragma unroll
    for (int kk = 0; kk < 4; ++kk)
      wf[g5][kk] = __builtin_bit_cast(
          bf16x8,
          *(const us8*)&wpd[(size_t)((g5 * 32 + ns) * 16 + (kh * 4 + kk)) * 512 + l * 8]);

  // ---- epilogue constants (threads 0..255 = waves 0..3) ----
  bool epi = tid < 256;
  int r = tid >> 5, j = tid & 31, jg = m * 32 + j, b = q * 8 + r;
  float bv[5];
#pragma unroll
  for (int g5 = 0; g5 < 5; ++g5) bv[g5] = bias[(g5 << 9) + jg];

  float c = 0.f;
  unsigned int xCur[6], xNext[6];             // px register double-buffer
  if (epi) {
    int t0 = d ? 511 : 0;
    const unsigned short* pp = pxd + ((size_t)((t0 << 5) + b)) * 3072 + jg;
#pragma unroll
    for (int q6 = 0; q6 < 6; ++q6) xNext[q6] = pp[q6 << 9];
  }

  // ---- chunk addressing ----
  bool lrow8 = (l & 15) < 8;
  int row8 = l & 7;
  int sel = l >> 4;
  int p0 = (sel == 1) ? 1 : (sel == 2) ? 2 : (sel == 3) ? 4 : 0;
  bool s1 = (sel == 1), s2 = (sel == 2);
  int coff[4];
#pragma unroll
  for (int kk = 0; kk < 4; ++kk)
    coff[kk] = (((kh * 4 + kk) * 8 + row8) * 6 + p0) * 16;
  int myc = l & 31, pbase = l & 32, prow = 2 * w + (l >> 5);  // publish (waves 0..3)

  for (int s = 0; s < 512; ++s) {
    int t = d ? (511 - s) : s;
    u32x4 ca[4], cb2[4];

    // ---- poll-on-data (skip s=0: h0 == 0) ----
    if (s > 0) {
      const char* cb = hxg + (size_t)(s & 1) * 98304;
      unsigned enc = (unsigned)(s | ((~s & 0xFFFF) << 16));
      long guard = 0;
      bool ok;
      do {
        if (lrow8) {
#pragma unroll
          for (int kk = 0; kk < 4; ++kk) chunk2_ld(cb + coff[kk], ca[kk], cb2[kk]);
        }
        asm volatile("s_waitcnt vmcnt(0)" ::: "memory");
        __builtin_amdgcn_sched_barrier(0);
        bool mine = true;
        if (lrow8) {
#pragma unroll
          for (int kk = 0; kk < 4; ++kk)
            mine = mine && (ca[kk][3] == enc) && (cb2[kk][3] == enc);
        }
        ok = (__all((int)mine) != 0);
      } while (!ok && ++guard < 300000L);
    }

    // ---- px: promote prefetch, issue next (compiler-managed waits) ----
    if (epi) {
#pragma unroll
      for (int i = 0; i < 6; ++i) xCur[i] = xNext[i];   // waits s-1's loads (old)
      if (s < 511) {
        int tn = d ? (511 - (s + 1)) : (s + 1);
        const unsigned short* pp = pxd + ((size_t)((tn << 5) + b)) * 3072 + jg;
#pragma unroll
        for (int q6 = 0; q6 < 6; ++q6) xNext[q6] = pp[q6 << 9];
      }
    }

    // ---- MFMA: M=8(pad16) x N=80 x K=128 per wave ----
    f32x4 acc[5];
#pragma unroll
    for (int g5 = 0; g5 < 5; ++g5) acc[g5] = (f32x4){0.f, 0.f, 0.f, 0.f};
    if (s > 0) {
#pragma unroll
      for (int kk = 0; kk < 4; ++kk) {
        u32x4 a = ca[kk], bb = cb2[kk], f;
        f[0] = s1 ? a[1] : (s2 ? a[2] : a[0]);
        f[1] = s1 ? a[2] : (s2 ? bb[0] : a[1]);
        f[2] = s1 ? bb[0] : (s2 ? bb[1] : a[2]);
        f[3] = s1 ? bb[1] : (s2 ? bb[2] : bb[0]);
        bf16x8 av = __builtin_bit_cast(bf16x8, f);
#pragma unroll
        for (int g5 = 0; g5 < 5; ++g5) acc[g5] = MFMA(av, wf[g5][kk], acc[g5]);
      }
    }
    if (l < 32) {
#pragma unroll
      for (int g5 = 0; g5 < 5; ++g5)
#pragma unroll
        for (int r4 = 0; r4 < 4; ++r4)
          part[s & 1][kh][(l >> 4) * 4 + r4][nh * 80 + g5 * 16 + (l & 15)] = acc[g5][r4];
    }
    __syncthreads();                          // the ONLY barrier per step

    // ---- epilogue + publish (threads 0..255) ----
    if (epi) {
      int cc0 = (j >> 4) * 80 + (j & 15);
      float ps_[5];
#pragma unroll
      for (int g5 = 0; g5 < 5; ++g5) {
        int cc = cc0 + g5 * 16;
        ps_[g5] = part[s & 1][0][r][cc] + part[s & 1][1][r][cc] +
                  part[s & 1][2][r][cc] + part[s & 1][3][r][cc] + bv[g5];
      }
      float x0 = bf2f(xCur[0]), x1 = bf2f(xCur[1]), x2 = bf2f(xCur[2]);
      float x3 = bf2f(xCur[3]), x4 = bf2f(xCur[4]), x5 = bf2f(xCur[5]);
      float iG = sigf(x0 + ps_[0]);
      float fG = sigf(x1 + ps_[1]);
      float gG = tanh_(x2 + ps_[2]);
      float oG = sigf(x3 + ps_[3]);
      float cn = iG * gG + fG * c;
      c = cn;
      float ht = oG * tanh_(cn);
      float rG = sigf(x4 + ps_[4]);
      ht = rG * ht + (1.f - rG) * x5;

      // publish FIRST (group's next-step critical path)
      if (s < 511) {
        unsigned int hbits = (unsigned int)f2bf(ht);
        unsigned int vv[6];
#pragma unroll
        for (int i = 0; i < 6; ++i)
          vv[i] = __shfl(hbits, (pbase + myc * 6 + i) & 63);
        unsigned int pw0 = vv[0] | (vv[1] << 16);
        unsigned int pw1 = vv[2] | (vv[3] << 16);
        unsigned int pw2 = vv[4] | (vv[5] << 16);
        if (myc == 5) { pw1 = 0; pw2 = 0; }
        if (myc < 6) {
          char* dst = hxg + (size_t)((s + 1) & 1) * 98304 +
                      (size_t)((m * 8 + prow) * 6 + myc) * 16;
          unsigned enc1 = (unsigned)((s + 1) | ((~(s + 1) & 0xFFFF) << 16));
          u32x4 pv = {pw0, pw1, pw2, enc1};
          pub16(dst, pv);
        }
      }

      size_t yo = ((size_t)(b * 512 + t)) * 1024 + d * 512 + jg;
      if (ybf) ybf[yo] = f2bf(ht);
      else     yf[yo] = ht;
      if (s == 511) {
        int fo = (layer * 32 + b) * 1024 + d * 512 + jg;
        finals[fo] = ht;            // final_h
        finals[65536 + fo] = cn;    // final_c
      }
    }
  }
}

// --------------------------- host ------------------------------------------

extern "C" void kernel_launch(void* const* d_in, const int* in_sizes, int n_in,
                              void* d_out, int out_size, void* d_ws, size_t ws_size,
                              hipStream_t stream) {
  (void)in_sizes; (void)n_in; (void)out_size; (void)ws_size;
  const float* x = (const float*)d_in[0];
  const float* Wx[4] = {(const float*)d_in[1], (const float*)d_in[4],
                        (const float*)d_in[7], (const float*)d_in[10]};
  const float* Wh[4] = {(const float*)d_in[2], (const float*)d_in[5],
                        (const float*)d_in[8], (const float*)d_in[11]};
  const float* bs[4] = {(const float*)d_in[3], (const float*)d_in[6],
                        (const float*)d_in[9], (const float*)d_in[12]};

  // ws: px + packed Wh + chunk exchange (~202.4 MiB)
  char* ws = (char*)d_ws;
  unsigned short* px   = (unsigned short*)(ws);
  unsigned short* whp  = (unsigned short*)(ws + 201326592);
  char*           hxc  = (char*)(ws + 211812352);

  // d_out doubles as scratch for transients (all dead before final y writes)
  char* ob = (char*)d_out;
  unsigned short* xbf  = (unsigned short*)(ob);             // 16 MiB, phase A
  unsigned short* wxt0 = (unsigned short*)(ob + 16777216);  // 6 MiB, phase A
  unsigned short* wxt1 = (unsigned short*)(ob + 33554432);  // 12 MiB
  unsigned short* a1bf = (unsigned short*)(ob);             // 32 MiB, phase B
  float* out = (float*)d_out;
  float* finals = out + 16777216;

  k_convert_x<<<8192, 256, 0, stream>>>(x, xbf, 2097152);
  k_pack_wxT<<<dim3(96, 32, 4), 256, 0, stream>>>(Wx[0], Wx[1], Wx[2], Wx[3], wxt0, wxt1);
  k_pack_whp<<<dim3(640, 4), 256, 0, stream>>>(Wh[0], Wh[1], Wh[2], Wh[3], whp);
  hipMemsetAsync(hxc, 0xFF, 393216, stream);   // never decodes as a valid seq

  for (int layer = 0; layer < 2; ++layer) {
    int K = layer ? 1024 : 512;
    const unsigned short* Ag = layer ? a1bf : xbf;
    const unsigned short* wxt = layer ? wxt1 : wxt0;
    k_gemm<<<dim3(128, 24, 2), 256, 0, stream>>>(Ag, wxt, px, K);
    k_persist<<<128, 512, 0, stream>>>(
        px, whp + (size_t)layer * 2621440, bs[layer * 2], bs[layer * 2 + 1],
        hxc, layer ? nullptr : a1bf, layer ? out : nullptr, finals, layer);
  }
}

// Round 10
// 3096.858 us; speedup vs baseline: 1.0782x; 1.0782x over previous
//
#include <hip/hip_runtime.h>

// ---------------------------------------------------------------------------
// StackedBidirectionalLstm  (B=32, T=512, IN=512, H=512, LAYERS=2, bidir, highway)
//
// Round 10 = round 9 (PASSING: poll-on-data MALL exchange, 8-wave WGs with
// register-resident Wh, one barrier/step, compiler-managed px double-buffer)
// + poll de-congestion:
//   - per-pair done-mask: lanes reload only chunk-pairs whose seq hasn't
//     matched (exec-masked) -> steady-state retry samples ~4x smaller
//   - s_sleep(1) between retry samples -> bounds spin-induced MALL traffic
//
//   ws layout (bytes), total ~202.4 MiB:
//     px   @ 0          201,326,592  ([2][512*32][3072] bf16, t-major)
//     whp  @ 201326592   10,485,760  (packed Wh fragments)
//     hxc  @ 211812352      393,216  ([2 layer][2 buf][8 grp][16 m][8 r][6 c]x16B)
//   d_out scratch: phase A xbf/wxt0/wxt1, phase B a1bf (as previous rounds).
// ---------------------------------------------------------------------------

typedef float f32x4 __attribute__((ext_vector_type(4)));
typedef __bf16 bf16x8 __attribute__((ext_vector_type(8)));
typedef unsigned short us8 __attribute__((ext_vector_type(8)));
typedef unsigned short us4 __attribute__((ext_vector_type(4)));
typedef unsigned int u32x4 __attribute__((ext_vector_type(4)));

__device__ __forceinline__ unsigned short f2bf(float f) {
  unsigned int u = __float_as_uint(f);
  u += 0x7FFFu + ((u >> 16) & 1u);            // round-to-nearest-even
  return (unsigned short)(u >> 16);
}
__device__ __forceinline__ float bf2f(unsigned int h) {
  return __uint_as_float(h << 16);
}
__device__ __forceinline__ float sigf(float x) { return 1.0f / (1.0f + __expf(-x)); }
__device__ __forceinline__ float tanh_(float x) { return 2.0f / (1.0f + __expf(-2.0f * x)) - 1.0f; }

#define MFMA(a, b, c) __builtin_amdgcn_mfma_f32_16x16x32_bf16((a), (b), (c), 0, 0, 0)
#define GLOAD_LDS(gp, lp)                                                           \
  __builtin_amdgcn_global_load_lds(                                                 \
      (const __attribute__((address_space(1))) void*)(gp),                          \
      (__attribute__((address_space(3))) void*)(lp), 16, 0, 0)

// Coherent (device/system-scope) 16B pair load; no waitcnt inside.
__device__ __forceinline__ void chunk2_ld(const char* p, u32x4& a, u32x4& b) {
  asm volatile("global_load_dwordx4 %0, %2, off sc0 sc1\n\t"
               "global_load_dwordx4 %1, %2, off offset:16 sc0 sc1"
               : "=&v"(a), "=&v"(b) : "v"(p) : "memory");
}
// Fire-and-forget coherent 16B publish.
__device__ __forceinline__ void pub16(char* p, u32x4 v) {
  asm volatile("global_store_dwordx4 %0, %1, off sc0 sc1" :: "v"(p), "v"(v) : "memory");
}

// --------------------------- prep kernels ----------------------------------

__global__ void k_convert_x(const float* __restrict__ x, unsigned short* __restrict__ xb, int n4) {
  int i = blockIdx.x * blockDim.x + threadIdx.x;
  if (i < n4) {
    float4 v = ((const float4*)x)[i];
    us4 o;
    o[0] = f2bf(v.x); o[1] = f2bf(v.y); o[2] = f2bf(v.z); o[3] = f2bf(v.w);
    ((us4*)xb)[i] = o;
  }
}

// Tiled transpose: WxT[n][k] = bf16(Wx[k][n]); z = layer*2+dir
__global__ __launch_bounds__(256) void k_pack_wxT(
    const float* __restrict__ W0, const float* __restrict__ W1,
    const float* __restrict__ W2, const float* __restrict__ W3,
    unsigned short* __restrict__ o01, unsigned short* __restrict__ o23) {
  int y = blockIdx.z;
  int K = (y >> 1) ? 1024 : 512;
  int kb = blockIdx.y * 32;
  if (kb >= K) return;
  const float* W = (y == 0) ? W0 : (y == 1) ? W1 : (y == 2) ? W2 : W3;
  unsigned short* o = (y >> 1) ? (o23 + (size_t)(y & 1) * 3072 * 1024)
                               : (o01 + (size_t)(y & 1) * 3072 * 512);
  __shared__ float tile[32][33];
  int nb = blockIdx.x * 32;
  int tx = threadIdx.x & 31, ty = threadIdx.x >> 5;   // ty 0..7
#pragma unroll
  for (int r = 0; r < 4; ++r)
    tile[ty + r * 8][tx] = W[(size_t)(kb + ty + r * 8) * 3072 + nb + tx];
  __syncthreads();
#pragma unroll
  for (int r = 0; r < 4; ++r)
    o[(size_t)(nb + ty + r * 8) * K + kb + tx] = f2bf(tile[tx][ty + r * 8]);
}

// Pack Wh (512x2560 f32) into MFMA B-fragments:
// out[(((g*32+ns)*16+ks)*64+lane)*8+e] = Wh[ks*32+(lane>>4)*8+e][g*512+ns*16+(lane&15)]
__global__ void k_pack_whp(const float* __restrict__ W0, const float* __restrict__ W1,
                           const float* __restrict__ W2, const float* __restrict__ W3,
                           unsigned short* __restrict__ out) {
  int y = blockIdx.y;
  const float* W = (y == 0) ? W0 : (y == 1) ? W1 : (y == 2) ? W2 : W3;
  unsigned short* o = out + (size_t)y * 1310720;
  int v = blockIdx.x * 256 + threadIdx.x;   // < 163840
  int lane = v & 63, ks = (v >> 6) & 15, ns = (v >> 10) & 31, g = v >> 15;
  int col = g * 512 + ns * 16 + (lane & 15);
  int kb = ks * 32 + ((lane >> 4) << 3);
  us8 vec;
#pragma unroll
  for (int e = 0; e < 8; ++e) vec[e] = f2bf(W[(size_t)(kb + e) * 2560 + col]);
  *(us8*)&o[(size_t)v * 8] = vec;
}

// --------------------------- bf16 GEMM -------------------------------------
// px[rr][col] with rr = t*32+b (t-major), from A[16384][K] @ Bt[3072][K]^T.
__global__ __launch_bounds__(256) void k_gemm(const unsigned short* __restrict__ A,
                                              const unsigned short* __restrict__ BtBase,
                                              unsigned short* __restrict__ CBase, int K) {
  __shared__ __align__(128) unsigned short As[128 * 32];
  __shared__ __align__(128) unsigned short Bs[128 * 32];
  const unsigned short* Bt = BtBase + (size_t)blockIdx.z * 3072 * K;
  unsigned short* C = CBase + (size_t)blockIdx.z * 16384 * 3072;
  int tid = threadIdx.x;
  int w = tid >> 6, l = tid & 63;
  int m0 = blockIdx.x * 128, n0 = blockIdx.y * 128;
  int wr = (w >> 1) * 64, wc = (w & 1) * 64;
  f32x4 acc[4][4];
#pragma unroll
  for (int i = 0; i < 4; ++i)
#pragma unroll
    for (int j = 0; j < 4; ++j) acc[i][j] = (f32x4){0.f, 0.f, 0.f, 0.f};

  for (int k0 = 0; k0 < K; k0 += 32) {
    __syncthreads();
#pragma unroll
    for (int half = 0; half < 2; ++half) {
      int r = w * 32 + half * 16 + (l >> 2);     // row within tile
      int gq = (l & 3) ^ (r & 3);                // swizzled source quarter
      GLOAD_LDS(A + (size_t)(m0 + r) * K + k0 + gq * 8, &As[(w * 32 + half * 16) * 32]);
      GLOAD_LDS(Bt + (size_t)(n0 + r) * K + k0 + gq * 8, &Bs[(w * 32 + half * 16) * 32]);
    }
    __syncthreads();
    bf16x8 af[4], bfr[4];
#pragma unroll
    for (int mi = 0; mi < 4; ++mi) {
      int r = wr + mi * 16 + (l & 15);
      int q = (l >> 4) ^ (r & 3);
      af[mi] = __builtin_bit_cast(bf16x8, *(const us8*)&As[r * 32 + q * 8]);
    }
#pragma unroll
    for (int ni = 0; ni < 4; ++ni) {
      int r = wc + ni * 16 + (l & 15);
      int q = (l >> 4) ^ (r & 3);
      bfr[ni] = __builtin_bit_cast(bf16x8, *(const us8*)&Bs[r * 32 + q * 8]);
    }
#pragma unroll
    for (int mi = 0; mi < 4; ++mi)
#pragma unroll
      for (int ni = 0; ni < 4; ++ni) acc[mi][ni] = MFMA(af[mi], bfr[ni], acc[mi][ni]);
  }
#pragma unroll
  for (int mi = 0; mi < 4; ++mi)
#pragma unroll
    for (int ni = 0; ni < 4; ++ni)
#pragma unroll
      for (int r4 = 0; r4 < 4; ++r4) {
        int row = m0 + wr + mi * 16 + (l >> 4) * 4 + r4;    // b*512 + t
        int rr = ((row & 511) << 5) + (row >> 9);           // t*32 + b
        int col = n0 + wc + ni * 16 + (l & 15);
        C[(size_t)rr * 3072 + col] = f2bf(acc[mi][ni][r4]);
      }
}

// --------------------------- persistent LSTM layer -------------------------
// 128 WGs x 512 threads = 8 groups (dir d, batch-quarter q) x 16 members.
// Member m owns hidden units m*32..m*32+31. 8 waves: kh = w&3 (K quarter),
// nh = w>>2 (hidden half); wf[5][4] = 80 VGPR/wave, register-resident.
// h exchange: 16B chunks {6 bf16 | enc(s)} via sc0 sc1 (MALL-coherent).
__global__ __launch_bounds__(512, 1) void k_persist(
    const unsigned short* __restrict__ px,    // [2][512*32][3072] bf16 t-major
    const unsigned short* __restrict__ wp,    // this layer's packed Wh (2 dirs)
    const float* __restrict__ bias_f, const float* __restrict__ bias_b,
    char* __restrict__ hxc,                   // [2 layer][2 buf][8 grp][16 m][8 r][6 c]x16B
    unsigned short* __restrict__ ybf,         // layer0: a1bf, else null
    float* __restrict__ yf,                   // layer1: d_out, else null
    float* __restrict__ finals,               // d_out + 16777216
    int layer) {
  __shared__ float part[2][4][8][160];        // 40 KiB, double-buffered
  int wg = blockIdx.x;
  int grp = wg >> 4, m = wg & 15;
  int d = grp & 1, q = grp >> 1;
  int tid = threadIdx.x;
  int w = tid >> 6, l = tid & 63;
  int kh = w & 3, nh = w >> 2;
  int ns = m * 2 + nh;                        // 16-hidden slice id (0..31)
  const unsigned short* wpd = wp + (size_t)d * 1310720;
  const unsigned short* pxd = px + (size_t)d * 16384 * 3072;
  const float* bias = d ? bias_b : bias_f;
  char* hxg = hxc + (size_t)layer * 196608 + (size_t)grp * 12288;

  // ---- Wh fragments register-resident: wf[gate][kk], this wave's K-quarter
  bf16x8 wf[5][4];
#pragma unroll
  for (int g5 = 0; g5 < 5; ++g5)
#pragma unroll
    for (int kk = 0; kk < 4; ++kk)
      wf[g5][kk] = __builtin_bit_cast(
          bf16x8,
          *(const us8*)&wpd[(size_t)((g5 * 32 + ns) * 16 + (kh * 4 + kk)) * 512 + l * 8]);

  // ---- epilogue constants (threads 0..255 = waves 0..3) ----
  bool epi = tid < 256;
  int r = tid >> 5, j = tid & 31, jg = m * 32 + j, b = q * 8 + r;
  float bv[5];
#pragma unroll
  for (int g5 = 0; g5 < 5; ++g5) bv[g5] = bias[(g5 << 9) + jg];

  float c = 0.f;
  unsigned int xCur[6], xNext[6];             // px register double-buffer
  if (epi) {
    int t0 = d ? 511 : 0;
    const unsigned short* pp = pxd + ((size_t)((t0 << 5) + b)) * 3072 + jg;
#pragma unroll
    for (int q6 = 0; q6 < 6; ++q6) xNext[q6] = pp[q6 << 9];
  }

  // ---- chunk addressing ----
  bool lrow8 = (l & 15) < 8;
  int row8 = l & 7;
  int sel = l >> 4;
  int p0 = (sel == 1) ? 1 : (sel == 2) ? 2 : (sel == 3) ? 4 : 0;
  bool s1 = (sel == 1), s2 = (sel == 2);
  int coff[4];
#pragma unroll
  for (int kk = 0; kk < 4; ++kk)
    coff[kk] = (((kh * 4 + kk) * 8 + row8) * 6 + p0) * 16;
  int myc = l & 31, pbase = l & 32, prow = 2 * w + (l >> 5);  // publish (waves 0..3)

  for (int s = 0; s < 512; ++s) {
    int t = d ? (511 - s) : s;
    u32x4 ca[4], cb2[4];

    // ---- poll-on-data (skip s=0: h0 == 0) ----
    if (s > 0) {
      const char* cb = hxg + (size_t)(s & 1) * 98304;
      unsigned enc = (unsigned)(s | ((~s & 0xFFFF) << 16));
      bool dn[4];
#pragma unroll
      for (int kk = 0; kk < 4; ++kk) dn[kk] = !lrow8;
      long guard = 0;
      bool ok;
      bool first = true;
      do {
        if (!first) __builtin_amdgcn_s_sleep(1);   // throttle retry traffic
        first = false;
#pragma unroll
        for (int kk = 0; kk < 4; ++kk)
          if (!dn[kk]) chunk2_ld(cb + coff[kk], ca[kk], cb2[kk]);
        asm volatile("s_waitcnt vmcnt(0)" ::: "memory");
        __builtin_amdgcn_sched_barrier(0);
        bool mine = true;
#pragma unroll
        for (int kk = 0; kk < 4; ++kk) {
          dn[kk] = dn[kk] || ((ca[kk][3] == enc) && (cb2[kk][3] == enc));
          mine = mine && dn[kk];
        }
        ok = (__all((int)mine) != 0);
      } while (!ok && ++guard < 300000L);
    }

    // ---- px: promote prefetch, issue next (compiler-managed waits) ----
    if (epi) {
#pragma unroll
      for (int i = 0; i < 6; ++i) xCur[i] = xNext[i];   // waits s-1's loads (old)
      if (s < 511) {
        int tn = d ? (511 - (s + 1)) : (s + 1);
        const unsigned short* pp = pxd + ((size_t)((tn << 5) + b)) * 3072 + jg;
#pragma unroll
        for (int q6 = 0; q6 < 6; ++q6) xNext[q6] = pp[q6 << 9];
      }
    }

    // ---- MFMA: M=8(pad16) x N=80 x K=128 per wave ----
    f32x4 acc[5];
#pragma unroll
    for (int g5 = 0; g5 < 5; ++g5) acc[g5] = (f32x4){0.f, 0.f, 0.f, 0.f};
    if (s > 0) {
#pragma unroll
      for (int kk = 0; kk < 4; ++kk) {
        u32x4 a = ca[kk], bb = cb2[kk], f;
        f[0] = s1 ? a[1] : (s2 ? a[2] : a[0]);
        f[1] = s1 ? a[2] : (s2 ? bb[0] : a[1]);
        f[2] = s1 ? bb[0] : (s2 ? bb[1] : a[2]);
        f[3] = s1 ? bb[1] : (s2 ? bb[2] : bb[0]);
        bf16x8 av = __builtin_bit_cast(bf16x8, f);
#pragma unroll
        for (int g5 = 0; g5 < 5; ++g5) acc[g5] = MFMA(av, wf[g5][kk], acc[g5]);
      }
    }
    if (l < 32) {
#pragma unroll
      for (int g5 = 0; g5 < 5; ++g5)
#pragma unroll
        for (int r4 = 0; r4 < 4; ++r4)
          part[s & 1][kh][(l >> 4) * 4 + r4][nh * 80 + g5 * 16 + (l & 15)] = acc[g5][r4];
    }
    __syncthreads();                          // the ONLY barrier per step

    // ---- epilogue + publish (threads 0..255) ----
    if (epi) {
      int cc0 = (j >> 4) * 80 + (j & 15);
      float ps_[5];
#pragma unroll
      for (int g5 = 0; g5 < 5; ++g5) {
        int cc = cc0 + g5 * 16;
        ps_[g5] = part[s & 1][0][r][cc] + part[s & 1][1][r][cc] +
                  part[s & 1][2][r][cc] + part[s & 1][3][r][cc] + bv[g5];
      }
      float x0 = bf2f(xCur[0]), x1 = bf2f(xCur[1]), x2 = bf2f(xCur[2]);
      float x3 = bf2f(xCur[3]), x4 = bf2f(xCur[4]), x5 = bf2f(xCur[5]);
      float iG = sigf(x0 + ps_[0]);
      float fG = sigf(x1 + ps_[1]);
      float gG = tanh_(x2 + ps_[2]);
      float oG = sigf(x3 + ps_[3]);
      float cn = iG * gG + fG * c;
      c = cn;
      float ht = oG * tanh_(cn);
      float rG = sigf(x4 + ps_[4]);
      ht = rG * ht + (1.f - rG) * x5;

      // publish FIRST (group's next-step critical path)
      if (s < 511) {
        unsigned int hbits = (unsigned int)f2bf(ht);
        unsigned int vv[6];
#pragma unroll
        for (int i = 0; i < 6; ++i)
          vv[i] = __shfl(hbits, (pbase + myc * 6 + i) & 63);
        unsigned int pw0 = vv[0] | (vv[1] << 16);
        unsigned int pw1 = vv[2] | (vv[3] << 16);
        unsigned int pw2 = vv[4] | (vv[5] << 16);
        if (myc == 5) { pw1 = 0; pw2 = 0; }
        if (myc < 6) {
          char* dst = hxg + (size_t)((s + 1) & 1) * 98304 +
                      (size_t)((m * 8 + prow) * 6 + myc) * 16;
          unsigned enc1 = (unsigned)((s + 1) | ((~(s + 1) & 0xFFFF) << 16));
          u32x4 pv = {pw0, pw1, pw2, enc1};
          pub16(dst, pv);
        }
      }

      size_t yo = ((size_t)(b * 512 + t)) * 1024 + d * 512 + jg;
      if (ybf) ybf[yo] = f2bf(ht);
      else     yf[yo] = ht;
      if (s == 511) {
        int fo = (layer * 32 + b) * 1024 + d * 512 + jg;
        finals[fo] = ht;            // final_h
        finals[65536 + fo] = cn;    // final_c
      }
    }
  }
}

// --------------------------- host ------------------------------------------

extern "C" void kernel_launch(void* const* d_in, const int* in_sizes, int n_in,
                              void* d_out, int out_size, void* d_ws, size_t ws_size,
                              hipStream_t stream) {
  (void)in_sizes; (void)n_in; (void)out_size; (void)ws_size;
  const float* x = (const float*)d_in[0];
  const float* Wx[4] = {(const float*)d_in[1], (const float*)d_in[4],
                        (const float*)d_in[7], (const float*)d_in[10]};
  const float* Wh[4] = {(const float*)d_in[2], (const float*)d_in[5],
                        (const float*)d_in[8], (const float*)d_in[11]};
  const float* bs[4] = {(const float*)d_in[3], (const float*)d_in[6],
                        (const float*)d_in[9], (const float*)d_in[12]};

  // ws: px + packed Wh + chunk exchange (~202.4 MiB)
  char* ws = (char*)d_ws;
  unsigned short* px   = (unsigned short*)(ws);
  unsigned short* whp  = (unsigned short*)(ws + 201326592);
  char*           hxc  = (char*)(ws + 211812352);

  // d_out doubles as scratch for transients (all dead before final y writes)
  char* ob = (char*)d_out;
  unsigned short* xbf  = (unsigned short*)(ob);             // 16 MiB, phase A
  unsigned short* wxt0 = (unsigned short*)(ob + 16777216);  // 6 MiB, phase A
  unsigned short* wxt1 = (unsigned short*)(ob + 33554432);  // 12 MiB
  unsigned short* a1bf = (unsigned short*)(ob);             // 32 MiB, phase B
  float* out = (float*)d_out;
  float* finals = out + 16777216;

  k_convert_x<<<8192, 256, 0, stream>>>(x, xbf, 2097152);
  k_pack_wxT<<<dim3(96, 32, 4), 256, 0, stream>>>(Wx[0], Wx[1], Wx[2], Wx[3], wxt0, wxt1);
  k_pack_whp<<<dim3(640, 4), 256, 0, stream>>>(Wh[0], Wh[1], Wh[2], Wh[3], whp);
  hipMemsetAsync(hxc, 0xFF, 393216, stream);   // never decodes as a valid seq

  for (int layer = 0; layer < 2; ++layer) {
    int K = layer ? 1024 : 512;
    const unsigned short* Ag = layer ? a1bf : xbf;
    const unsigned short* wxt = layer ? wxt1 : wxt0;
    k_gemm<<<dim3(128, 24, 2), 256, 0, stream>>>(Ag, wxt, px, K);
    k_persist<<<128, 512, 0, stream>>>(
        px, whp + (size_t)layer * 2621440, bs[layer * 2], bs[layer * 2 + 1],
        hxc, layer ? nullptr : a1bf, layer ? out : nullptr, finals, layer);
  }
}